// Round 3
// baseline (2159.248 us; speedup 1.0000x reference)
//
#include <hip/hip_runtime.h>

#define NLVL 6
#define NN   32768
#define KFAN 8
#define FDIM 32
#define HDIM 256

typedef __attribute__((ext_vector_type(4))) float f32x4;
typedef __attribute__((ext_vector_type(8))) _Float16 f16x8;
typedef __attribute__((ext_vector_type(4))) unsigned short u16x4;

__device__ __forceinline__ float h2f(unsigned short u) {
    _Float16 h; __builtin_memcpy(&h, &u, 2); return (float)h;
}
__device__ __forceinline__ unsigned short f2h(float f) {
    _Float16 h = (_Float16)f;   // RNE
    unsigned short u; __builtin_memcpy(&u, &h, 2); return u;
}
__device__ __forceinline__ float tanh_fast(float x) {
    float e = __expf(2.0f * x);
    return 1.0f - 2.0f / (e + 1.0f);
}
__device__ __forceinline__ void gload16(const void* g, void* l) {
    __builtin_amdgcn_global_load_lds((const __attribute__((address_space(1))) void*)g,
                                     (__attribute__((address_space(3))) void*)l, 16, 0, 0);
}

// ---------------------------------------------------------------------------
// One GEMM layer: acc[MFR][4] += sA[rbase.., :KLEN] @ Wg[wcol.., :KLEN]^T
// A from LDS (XOR-swizzled rows of ROWB bytes), B streamed global->regs
// (weights are L2-resident; every block reads the same panels).
// Named double-buffer (rule #20 safe), full unroll over K slices.
// ---------------------------------------------------------------------------
template<int KLEN, int ROWB, int MFR>
__device__ __forceinline__ void layer_mm(const unsigned short* sA,
                                         const unsigned short* __restrict__ Wg, int ldw,
                                         int rbase, int wcol, int lane,
                                         f32x4 (&acc)[MFR][4])
{
    const int fr = lane & 15, fq = lane >> 4;
    #pragma unroll
    for (int m = 0; m < MFR; ++m)
        #pragma unroll
        for (int n = 0; n < 4; ++n)
            acc[m][n] = (f32x4){0.f, 0.f, 0.f, 0.f};

    constexpr int NKS = KLEN / 32;
    f16x8 avA[MFR], avB[MFR], bvA[4], bvB[4];

    auto ldB = [&](int ks, f16x8* bv) {
        #pragma unroll
        for (int n = 0; n < 4; ++n)
            bv[n] = *(const f16x8*)(Wg + (size_t)(wcol + n * 16 + fr) * ldw + ks * 32 + fq * 8);
    };
    auto ldA = [&](int ks, f16x8* av) {
        #pragma unroll
        for (int m = 0; m < MFR; ++m) {
            const int rr = rbase + m * 16 + fr;
            const int byt = rr * ROWB + ((ks * 64 + fq * 16) ^ ((rr & 7) << 4));
            av[m] = *(const f16x8*)((const char*)sA + byt);
        }
    };
    auto mm = [&](f16x8* av, f16x8* bv) {
        #pragma unroll
        for (int m = 0; m < MFR; ++m)
            #pragma unroll
            for (int n = 0; n < 4; ++n)
                acc[m][n] = __builtin_amdgcn_mfma_f32_16x16x32_f16(av[m], bv[n], acc[m][n], 0, 0, 0);
    };

    ldA(0, avA); ldB(0, bvA);
    #pragma unroll
    for (int s = 0; s < NKS / 2; ++s) {
        ldA(2 * s + 1, avB); ldB(2 * s + 1, bvB);
        mm(avA, bvA);
        if (2 * s + 2 < NKS) { ldA(2 * s + 2, avA); ldB(2 * s + 2, bvA); }
        mm(avB, bvB);
    }
}

// ---------------------------------------------------------------------------
// Fused 3-layer resnet: out = tanh(W3 @ (tanh(W2@tanh(W1@x+b1)+b2) + x) + b3)
// (outer tanh included — every call site in the reference wraps in tanh).
// BM rows/block, 8 waves. x staged to sX (or gather-summed if GATHER);
// h1/h2 live in sH. Layer-1 K-extent = K1 (comb-big: x = [e,0] -> K1=256).
// ---------------------------------------------------------------------------
template<int BM, int KD, int K1, bool GATHER, bool F32OUT>
__global__ __launch_bounds__(512, 2)
void resnet_fused(const unsigned short* __restrict__ X, int ldx,
                  const int* __restrict__ gidx,
                  const unsigned short* __restrict__ gsrc,
                  const unsigned short* __restrict__ W1, const float* __restrict__ b1,
                  const unsigned short* __restrict__ W2, const float* __restrict__ b2,
                  const unsigned short* __restrict__ W3, const float* __restrict__ b3,
                  unsigned short* __restrict__ outB, int ldo,
                  float* __restrict__ outF)
{
    __shared__ __align__(16) unsigned short sX[BM * K1];
    __shared__ __align__(16) unsigned short sH[BM * KD];
    constexpr int ROWBX = K1 * 2, ROWBH = KD * 2;

    const int tid = threadIdx.x, lane = tid & 63, wid = tid >> 6;
    const int brow = blockIdx.x * BM;
    const int fr = lane & 15, fq = lane >> 4;

    // ---- stage x -> sX (swizzled) ----
    if (GATHER) {
        constexpr int CB = K1 / 8;
        for (int i = tid; i < BM * CB; i += 512) {
            const int row = i / CB, cb = i % CB;
            const int* ip = gidx + (size_t)(brow + row) * KFAN;
            float s[8] = {0.f, 0.f, 0.f, 0.f, 0.f, 0.f, 0.f, 0.f};
            #pragma unroll
            for (int k = 0; k < KFAN; ++k) {
                f16x8 v = *(const f16x8*)(gsrc + (size_t)ip[k] * HDIM + cb * 8);
                #pragma unroll
                for (int j = 0; j < 8; ++j) s[j] += (float)v[j];
            }
            f16x8 o;
            #pragma unroll
            for (int j = 0; j < 8; ++j) o[j] = (_Float16)s[j];
            *(f16x8*)((char*)sX + row * ROWBX + ((cb * 16) ^ ((row & 7) << 4))) = o;
        }
    } else {
        constexpr int ROUNDS = BM * K1 * 2 / (512 * 16);
        #pragma unroll
        for (int r = 0; r < ROUNDS; ++r) {
            const int lin = (r * 512 + tid) * 16;        // this lane's dest byte
            const int row = lin / ROWBX;
            const int cb  = (lin % ROWBX) >> 4;
            const int scb = cb ^ (row & 7);              // pre-swizzled source block
            gload16(X + (size_t)(brow + row) * ldx + scb * 8,
                    (char*)sX + (lin - lane * 16));      // wave-uniform LDS base
        }
    }
    __syncthreads();

    // ---- layer 1: h1 = tanh(x @ W1^T + b1) -> sH ----
    constexpr int NWC12 = KD / 64;
    const int wc12 = (wid % NWC12) * 64;
    const int rb12 = (wid / NWC12) * 64;
    {
        f32x4 a1[4][4];
        layer_mm<K1, ROWBX, 4>(sX, W1, KD, rb12, wc12, lane, a1);
        #pragma unroll
        for (int m = 0; m < 4; ++m)
            #pragma unroll
            for (int n = 0; n < 4; ++n) {
                const int col = wc12 + n * 16 + fr;
                const float bb = b1[col];
                #pragma unroll
                for (int j = 0; j < 4; ++j) {
                    const int row = rb12 + m * 16 + fq * 4 + j;
                    const float v = tanh_fast(a1[m][n][j] + bb);
                    *(unsigned short*)((char*)sH + row * ROWBH + ((col * 2) ^ ((row & 7) << 4))) = f2h(v);
                }
            }
    }
    __syncthreads();

    // ---- layer 2: h2 = tanh(h1 @ W2^T + b2) + x -> sH (after barrier) ----
    {
        f32x4 a2[4][4];
        layer_mm<KD, ROWBH, 4>(sH, W2, KD, rb12, wc12, lane, a2);
        #pragma unroll
        for (int m = 0; m < 4; ++m)
            #pragma unroll
            for (int n = 0; n < 4; ++n) {
                const int col = wc12 + n * 16 + fr;
                const float bb = b2[col];
                #pragma unroll
                for (int j = 0; j < 4; ++j) {
                    const int row = rb12 + m * 16 + fq * 4 + j;
                    float v = tanh_fast(a2[m][n][j] + bb);
                    if (col < K1)
                        v += h2f(*(const unsigned short*)((const char*)sX + row * ROWBX + ((col * 2) ^ ((row & 7) << 4))));
                    a2[m][n][j] = v;
                }
            }
        __syncthreads();   // all waves done READING sH before overwrite
        #pragma unroll
        for (int m = 0; m < 4; ++m)
            #pragma unroll
            for (int n = 0; n < 4; ++n) {
                const int col = wc12 + n * 16 + fr;
                #pragma unroll
                for (int j = 0; j < 4; ++j) {
                    const int row = rb12 + m * 16 + fq * 4 + j;
                    *(unsigned short*)((char*)sH + row * ROWBH + ((col * 2) ^ ((row & 7) << 4))) = f2h(a2[m][n][j]);
                }
            }
    }
    __syncthreads();

    // ---- layer 3: out = tanh((h2+x) @ W3^T + b3), N=256 ----
    {
        constexpr int WM3 = BM / 2, MFR3 = WM3 / 16;
        const int wc3 = (wid & 3) * 64;
        const int rb3 = (wid >> 2) * WM3;
        f32x4 a3[MFR3][4];
        layer_mm<KD, ROWBH, MFR3>(sH, W3, KD, rb3, wc3, lane, a3);
        #pragma unroll
        for (int m = 0; m < MFR3; ++m)
            #pragma unroll
            for (int n = 0; n < 4; ++n) {
                const int col = wc3 + n * 16 + fr;
                const float bb = b3[col];
                #pragma unroll
                for (int j = 0; j < 4; ++j) {
                    const int row = rb3 + m * 16 + fq * 4 + j;
                    const float v = tanh_fast(a3[m][n][j] + bb);
                    const size_t gr = (size_t)(brow + row);
                    outB[gr * ldo + col] = f2h(v);
                    if (F32OUT) outF[gr * HDIM + col] = v;
                }
            }
    }
}

// ---------------------------------------------------------------------------
// Embed: e = tanh(feats[N,32] @ We[256,32]^T + be) -> fp16 (+ optional f32)
// ---------------------------------------------------------------------------
template<bool F32OUT>
__global__ __launch_bounds__(256)
void embed_kernel(const float* __restrict__ feats,
                  const float* __restrict__ We,
                  const float* __restrict__ be,
                  unsigned short* __restrict__ outB, int ldo,
                  float* __restrict__ outF)
{
    __shared__ float sW[256 * 33];   // +1 pad: kills bank conflicts on t*33+k
    __shared__ float sF[16 * 32];
    const int t = threadIdx.x;
    #pragma unroll
    for (int i = 0; i < 32; ++i) {
        int idx = t + 256 * i;
        sW[(idx >> 5) * 33 + (idx & 31)] = We[idx];
    }
    const size_t base = (size_t)blockIdx.x * 16;
    for (int i = t; i < 16 * 32; i += 256) sF[i] = feats[base * 32 + i];
    __syncthreads();

    const float bb = be[t];
    for (int r = 0; r < 16; ++r) {
        float a = bb;
        #pragma unroll
        for (int k = 0; k < 32; ++k) a += sF[r * 32 + k] * sW[t * 33 + k];
        const float v = tanh_fast(a);
        const size_t row = base + r;
        outB[row * ldo + t] = f2h(v);
        if (F32OUT) outF[row * HDIM + t] = v;
    }
}

// ---------------------------------------------------------------------------
// fp32 -> fp16 weight conversion
// ---------------------------------------------------------------------------
__global__ __launch_bounds__(256)
void cvt_kernel(const float* __restrict__ in, unsigned short* __restrict__ out, int n4)
{
    const int i = blockIdx.x * 256 + threadIdx.x;
    if (i >= n4) return;
    const float4 v = ((const float4*)in)[i];
    u16x4 o;
    o[0] = f2h(v.x); o[1] = f2h(v.y); o[2] = f2h(v.z); o[3] = f2h(v.w);
    ((u16x4*)out)[i] = o;
}

// ---------------------------------------------------------------------------
extern "C" void kernel_launch(void* const* d_in, const int* in_sizes, int n_in,
                              void* d_out, int out_size, void* d_ws, size_t ws_size,
                              hipStream_t stream)
{
    const float* feats    = (const float*)d_in[0];
    const int*   pred_idx = (const int*)d_in[1];
    const float* We       = (const float*)d_in[2];
    const float* be       = (const float*)d_in[3];
    const float* rs_W1    = (const float*)d_in[4];
    const float* rs_b1    = (const float*)d_in[5];
    const float* rs_W2    = (const float*)d_in[6];
    const float* rs_b2    = (const float*)d_in[7];
    const float* rs_W3    = (const float*)d_in[8];
    const float* rs_b3    = (const float*)d_in[9];
    const float* rc_W1    = (const float*)d_in[10];
    const float* rc_b1    = (const float*)d_in[11];
    const float* rc_W2    = (const float*)d_in[12];
    const float* rc_b2    = (const float*)d_in[13];
    const float* rc_W3    = (const float*)d_in[14];
    const float* rc_b3    = (const float*)d_in[15];
    float* out = (float*)d_out;

    // ---- workspace layout (fp16 everywhere) ----
    char* ws = (char*)d_ws;
    size_t off = 0;
    auto alloc = [&](size_t bytes) -> unsigned short* {
        unsigned short* p = (unsigned short*)(ws + off);
        off += (bytes + 255) & ~(size_t)255;
        return p;
    };
    unsigned short* rcW1b = alloc((size_t)6 * 512 * 512 * 2);
    unsigned short* rcW2b = alloc((size_t)6 * 512 * 512 * 2);
    unsigned short* rcW3b = alloc((size_t)6 * 256 * 512 * 2);
    unsigned short* rsW1b = alloc((size_t)12 * 256 * 256 * 2);
    unsigned short* rsW2b = alloc((size_t)12 * 256 * 256 * 2);
    unsigned short* rsW3b = alloc((size_t)12 * 256 * 256 * 2);
    unsigned short* xcat  = alloc((size_t)NN * 256 * 2);   // e (embed out)
    unsigned short* p0    = alloc((size_t)NN * 512 * 2);   // x2cat = [e', r]
    unsigned short* Tb    = alloc((size_t)NN * 256 * 2);   // big-resnet outputs
    unsigned short* q0    = alloc((size_t)NN * 256 * 2);   // msg chain temp
    unsigned short* ebfA  = alloc((size_t)NN * 256 * 2);
    unsigned short* ebfB  = alloc((size_t)NN * 256 * 2);
    (void)ws_size; (void)in_sizes; (void)n_in; (void)out_size;

    // ---- convert weights fp32 -> fp16 ----
    auto cvt = [&](const float* src, unsigned short* dst, int n) {
        int n4 = n / 4;
        cvt_kernel<<<dim3((n4 + 255) / 256), dim3(256), 0, stream>>>(src, dst, n4);
    };
    cvt(rc_W1, rcW1b, 6 * 512 * 512);
    cvt(rc_W2, rcW2b, 6 * 512 * 512);
    cvt(rc_W3, rcW3b, 6 * 256 * 512);
    cvt(rs_W1, rsW1b, 12 * 256 * 256);
    cvt(rs_W2, rsW2b, 12 * 256 * 256);
    cvt(rs_W3, rsW3b, 12 * 256 * 256);

    // ---- fused resnet launchers ----
    auto smallRN = [&](int i, const unsigned short* x, int ldx,
                       unsigned short* ob, int ldo, float* of,
                       const int* gidx, const unsigned short* gsrc) {
        const unsigned short* w1 = rsW1b + (size_t)i * 256 * 256;
        const unsigned short* w2 = rsW2b + (size_t)i * 256 * 256;
        const unsigned short* w3 = rsW3b + (size_t)i * 256 * 256;
        const float* B1 = rs_b1 + i * 256;
        const float* B2 = rs_b2 + i * 256;
        const float* B3 = rs_b3 + i * 256;
        if (gidx)
            resnet_fused<128, 256, 256, true, false><<<dim3(NN / 128), dim3(512), 0, stream>>>(
                nullptr, 0, gidx, gsrc, w1, B1, w2, B2, w3, B3, ob, ldo, nullptr);
        else if (of)
            resnet_fused<128, 256, 256, false, true><<<dim3(NN / 128), dim3(512), 0, stream>>>(
                x, ldx, nullptr, nullptr, w1, B1, w2, B2, w3, B3, ob, ldo, of);
        else
            resnet_fused<128, 256, 256, false, false><<<dim3(NN / 128), dim3(512), 0, stream>>>(
                x, ldx, nullptr, nullptr, w1, B1, w2, B2, w3, B3, ob, ldo, nullptr);
    };
    auto bigRN = [&](int i, bool halfK, const unsigned short* x, int ldx, unsigned short* ob) {
        const unsigned short* w1 = rcW1b + (size_t)i * 512 * 512;
        const unsigned short* w2 = rcW2b + (size_t)i * 512 * 512;
        const unsigned short* w3 = rcW3b + (size_t)i * 256 * 512;
        const float* B1 = rc_b1 + i * 512;
        const float* B2 = rc_b2 + i * 512;
        const float* B3 = rc_b3 + i * 256;
        if (halfK)
            resnet_fused<64, 512, 256, false, false><<<dim3(NN / 64), dim3(512), 0, stream>>>(
                x, ldx, nullptr, nullptr, w1, B1, w2, B2, w3, B3, ob, 256, nullptr);
        else
            resnet_fused<64, 512, 512, false, false><<<dim3(NN / 64), dim3(512), 0, stream>>>(
                x, ldx, nullptr, nullptr, w1, B1, w2, B2, w3, B3, ob, 256, nullptr);
    };

    unsigned short* ebp = ebfA;   // embeds[l-1] (fp16)
    unsigned short* ebc = ebfB;   // embeds[l]

    // level 0
    embed_kernel<true><<<dim3(NN / 16), dim3(256), 0, stream>>>(
        feats, We, be, ebp, 256, out);

    for (int l = 1; l < NLVL; ++l) {
        const int d = (l - 1 < 2) ? (l - 1) : 2;
        const float* fl = feats + (size_t)l * NN * FDIM;
        const int* idx_l = pred_idx + (size_t)(l - 1) * NN * KFAN;

        // e = tanh(feats @ We^T + be)
        embed_kernel<false><<<dim3(NN / 16), dim3(256), 0, stream>>>(
            fl, We, be, xcat, 256, nullptr);

        // comb: T = tanh(big(3+d, [e,0])) [K1=256]; e' = tanh(small(9+d, T))
        bigRN(3 + d, true, xcat, 256, Tb);
        smallRN(9 + d, Tb, 256, p0, 512, nullptr, nullptr, nullptr);        // e' -> x2[:, :256]

        // msg: r = tanh(small(2d+1, tanh(small(2d, gathersum(ebp)))))
        smallRN(2 * d,     nullptr, 0, q0, 256, nullptr, idx_l, ebp);        // gather fused
        smallRN(2 * d + 1, q0, 256, p0 + 256, 512, nullptr, nullptr, nullptr); // r -> x2[:, 256:]

        // node: T = tanh(big(d, [e', r])); e = tanh(small(6+d, T))
        bigRN(d, false, p0, 512, Tb);
        smallRN(6 + d, Tb, 256, ebc, 256, out + (size_t)l * NN * HDIM, nullptr, nullptr);

        unsigned short* tmp = ebp; ebp = ebc; ebc = tmp;
    }
}